// Round 6
// baseline (1190.354 us; speedup 1.0000x reference)
//
#include <hip/hip_runtime.h>
#include <hip/hip_bf16.h>
#include <stdint.h>

// Problem constants: B=4, S=1024, D=1024, H=16, HD=64, L=6, OUT=512
#define BATCH 4
#define SEQ   1024
#define DIM   1024
#define NH    16
#define HDIM  64
#define NLAYER 6
#define NOUT  512
#define NTOK  (BATCH*SEQ)          // 4096 rows
#define LOG2E 1.44269504088896f
#define NEG_BIG (-1e30f)
#define VTS   72                   // padded LDS row stride (elements) for V^T / P

using bf16 = __hip_bfloat16;
typedef __attribute__((ext_vector_type(4))) float f32x4;
typedef __attribute__((ext_vector_type(8))) short bf16x8;

typedef __attribute__((address_space(1))) void as1_void;
typedef __attribute__((address_space(3))) void as3_void;

__device__ __forceinline__ float bf2f(short u) {
  union { unsigned int i; float f; } c;
  c.i = ((unsigned int)(unsigned short)u) << 16;
  return c.f;
}

__device__ __forceinline__ short f2bs(float f) {
  bf16 h = __float2bfloat16(f);
  return *(short*)&h;
}

// inf-free exp: clamp exponent so exp2f never sees huge/inf args (fast-math safe)
__device__ __forceinline__ float exp_clamped(float x) {
  return exp2f(fmaxf(x, -100.f) * LOG2E);
}

// flag-dependent scalar load: fp32 buffer or bf16 buffer
__device__ __forceinline__ float loadf(const void* p, size_t i, bool f32) {
  return f32 ? ((const float*)p)[i] : __bfloat162float(((const bf16*)p)[i]);
}

// async global->LDS, 16B per lane; LDS dest is wave-uniform base + lane*16
__device__ __forceinline__ void g2l16(const void* g, void* l) {
  __builtin_amdgcn_global_load_lds((const as1_void*)g, (as3_void*)l, 16, 0, 0);
}

// ---------------------------------------------------------------------------
// dtype sniffer: flag = 1 -> inputs are fp32 ; flag = 0 -> inputs are bf16
// ---------------------------------------------------------------------------
__global__ void sniff(const unsigned int* __restrict__ w, int* __restrict__ flag) {
  const int lane = threadIdx.x;            // 64 threads
  const unsigned int word = w[lane];
  const int e2 = (word >> 7) & 0xFF;
  const bool bf16ish = (e2 >= 0x60) && (e2 <= 0x8F);
  const unsigned long long m = __ballot(bf16ish);
  if (lane == 0) *flag = (__popcll(m) >= 48) ? 0 : 1;
}

// convert one weight tensor to bf16 workspace (copy if already bf16)
__global__ __launch_bounds__(256) void convert_w(const void* __restrict__ src,
                                                 bf16* __restrict__ dst,
                                                 const int* __restrict__ flag) {
  const size_t i = ((size_t)blockIdx.x * 256 + threadIdx.x) * 8;
  if (*flag) {
    const float* s = (const float*)src + i;
#pragma unroll
    for (int e = 0; e < 8; ++e) dst[i + e] = __float2bfloat16(s[e]);
  } else {
    *(bf16x8*)(dst + i) = *(const bf16x8*)((const bf16*)src + i);
  }
}

// ---------------------------------------------------------------------------
// GEMM: C[M,N] = A[M,K] * W[N,K]^T (m97 structure, verified round 4/5)
// EPI 0: store bf16. EPI 1: fp32 atomic += (split-K safe).
// EPI 2: flag ? fp32 store : bf16 store.
// ---------------------------------------------------------------------------
template<int EPI>
__device__ __forceinline__ void gemm_body(const bf16* __restrict__ A,
                                          const bf16* __restrict__ W,
                                          void* __restrict__ C,
                                          const int* __restrict__ flag,
                                          int N, int m0, int n0,
                                          int kstart, int kend) {
  __shared__ __align__(16) bf16 lA[128 * 32];
  __shared__ __align__(16) bf16 lB[128 * 32];
  const int tid  = threadIdx.x;
  const int wave = tid >> 6;
  const int lane = tid & 63;
  const int quad = lane >> 4;
  const int l16  = lane & 15;
  const int wm = (wave >> 1) * 64;
  const int wn = (wave & 1) * 64;
  const int K = DIM;

  const int r0 = tid >> 2;
  const int c0 = (tid & 3) * 8;
  const int r1 = (tid + 256) >> 2;

  bool f32out = false;
  if (EPI == 2) f32out = (*flag != 0);

  f32x4 acc[4][4];
#pragma unroll
  for (int i = 0; i < 4; ++i)
#pragma unroll
    for (int j = 0; j < 4; ++j) acc[i][j] = (f32x4){0.f, 0.f, 0.f, 0.f};

  for (int k0 = kstart; k0 < kend; k0 += 32) {
    __syncthreads();
    g2l16(A + (size_t)(m0 + r0) * K + k0 + c0, lA + 512 * wave);
    g2l16(A + (size_t)(m0 + r1) * K + k0 + c0, lA + 2048 + 512 * wave);
    g2l16(W + (size_t)(n0 + r0) * K + k0 + c0, lB + 512 * wave);
    g2l16(W + (size_t)(n0 + r1) * K + k0 + c0, lB + 2048 + 512 * wave);
    __builtin_amdgcn_s_waitcnt(0);
    __syncthreads();

    bf16x8 af[4], bfr[4];
#pragma unroll
    for (int i = 0; i < 4; ++i) {
      af[i]  = *(const bf16x8*)(lA + (wm + i * 16 + l16) * 32 + quad * 8);
      bfr[i] = *(const bf16x8*)(lB + (wn + i * 16 + l16) * 32 + quad * 8);
    }
#pragma unroll
    for (int i = 0; i < 4; ++i)
#pragma unroll
      for (int j = 0; j < 4; ++j)
        acc[i][j] = __builtin_amdgcn_mfma_f32_16x16x32_bf16(af[i], bfr[j], acc[i][j], 0, 0, 0);
  }

  // C/D layout: col = lane&15, row = quad*4 + reg
#pragma unroll
  for (int i = 0; i < 4; ++i) {
    const int rowb = m0 + wm + i * 16 + quad * 4;
#pragma unroll
    for (int j = 0; j < 4; ++j) {
      const int col = n0 + wn + j * 16 + l16;
#pragma unroll
      for (int r = 0; r < 4; ++r) {
        const size_t idx = (size_t)(rowb + r) * N + col;
        const float v = acc[i][j][r];
        if (EPI == 0) ((bf16*)C)[idx] = __float2bfloat16(v);
        else if (EPI == 1) unsafeAtomicAdd(&((float*)C)[idx], v);
        else { if (f32out) ((float*)C)[idx] = v; else ((bf16*)C)[idx] = __float2bfloat16(v); }
      }
    }
  }
}

__global__ __launch_bounds__(256) void gemm_out(const bf16* __restrict__ A,
                                                const bf16* __restrict__ W,
                                                void* __restrict__ C,
                                                const int* __restrict__ flag) {
  gemm_body<2>(A, W, C, flag, NOUT, blockIdx.y * 128, blockIdx.x * 128, 0, DIM);
}

// split-K x2: blockIdx.z selects K-half; atomic += epilogue
__global__ __launch_bounds__(256) void gemm_add(const bf16* __restrict__ A,
                                                const bf16* __restrict__ W,
                                                float* __restrict__ C) {
  const int ks = blockIdx.z * (DIM / 2);
  gemm_body<1>(A, W, C, nullptr, DIM, blockIdx.y * 128, blockIdx.x * 128,
               ks, ks + DIM / 2);
}

__global__ __launch_bounds__(256) void gemm_qkv(const bf16* __restrict__ A,
                                                const bf16* __restrict__ wq,
                                                const bf16* __restrict__ wk,
                                                const bf16* __restrict__ wv,
                                                bf16* __restrict__ q,
                                                bf16* __restrict__ k,
                                                bf16* __restrict__ v) {
  const int gx = blockIdx.x;
  const int sel = gx >> 3;
  const int n0 = (gx & 7) * 128;
  const bf16* W = (sel == 0) ? wq : (sel == 1 ? wk : wv);
  bf16* C = (sel == 0) ? q : (sel == 1 ? k : v);
  gemm_body<0>(A, W, C, nullptr, DIM, blockIdx.y * 128, n0, 0, DIM);
}

// ---------------------------------------------------------------------------
// h = x + pe  (flag-dependent input dtype), fp32 residual stream
// ---------------------------------------------------------------------------
__global__ __launch_bounds__(256) void add_pe(const void* __restrict__ x,
                                              const void* __restrict__ pe,
                                              float* __restrict__ h,
                                              const int* __restrict__ flag) {
  const bool f32 = (*flag != 0);
  const size_t i = (size_t)blockIdx.x * 256 + threadIdx.x;
  h[i] = loadf(x, i, f32) + loadf(pe, i & (SEQ * DIM - 1), f32);
}

// ---------------------------------------------------------------------------
// LayerNorm over D=1024: one 256-thread block per row, fp32 in, bf16 out.
// ---------------------------------------------------------------------------
__global__ __launch_bounds__(256) void layernorm(const float* __restrict__ x,
                                                 const void* __restrict__ g,
                                                 const void* __restrict__ b,
                                                 int loff,
                                                 bf16* __restrict__ y,
                                                 const int* __restrict__ flag) {
  const bool f32 = (*flag != 0);
  const int row = blockIdx.x;
  const int tid = threadIdx.x;
  const int wave = tid >> 6;
  const float* xr = x + (size_t)row * DIM;
  __shared__ float red[8];

  float v[4];
  float s = 0.f;
#pragma unroll
  for (int i = 0; i < 4; ++i) { v[i] = xr[tid + 256 * i]; s += v[i]; }
#pragma unroll
  for (int off = 32; off >= 1; off >>= 1) s += __shfl_xor(s, off);
  if ((tid & 63) == 0) red[wave] = s;
  __syncthreads();
  const float mu = (red[0] + red[1] + red[2] + red[3]) * (1.f / DIM);

  float vs = 0.f;
#pragma unroll
  for (int i = 0; i < 4; ++i) { const float d = v[i] - mu; vs += d * d; }
#pragma unroll
  for (int off = 32; off >= 1; off >>= 1) vs += __shfl_xor(vs, off);
  if ((tid & 63) == 0) red[4 + wave] = vs;
  __syncthreads();
  const float var = (red[4] + red[5] + red[6] + red[7]) * (1.f / DIM);
  const float rs = rsqrtf(var + 1e-5f);

#pragma unroll
  for (int i = 0; i < 4; ++i) {
    const int d = tid + 256 * i;
    const float gv = loadf(g, (size_t)loff + d, f32);
    const float bv = loadf(b, (size_t)loff + d, f32);
    y[(size_t)row * DIM + d] = __float2bfloat16((v[i] - mu) * rs * gv + bv);
  }
}

// ---------------------------------------------------------------------------
// MFMA flash attention, FIXED-MAX softmax (m=0).
// Scores bounded: |s| <= |q||k|/8 ~ 26 << 88 (fp32 exp overflow), so the
// softmax shift is unnecessary -> no max reduction, no alpha rescale, and the
// l-sum accumulates per-lane, reduced ONCE at the end.
// Block = (b, h, 64 q-rows); 4 waves, 16 q-rows/wave.
// ---------------------------------------------------------------------------
__global__ __launch_bounds__(256, 2) void attn_flash(const bf16* __restrict__ q,
                                                     const bf16* __restrict__ k,
                                                     const bf16* __restrict__ v,
                                                     bf16* __restrict__ o) {
  __shared__ __align__(16) short lK[64 * 64];        // [key][dim], chunk-swizzled
  __shared__ __align__(16) short lVT[64 * VTS];      // [dim][key], kk-swizzled
  __shared__ __align__(16) short lP[4 * 16 * VTS];   // per-wave P, padded

  const int idx = blockIdx.x;
  const int qt = (SEQ / 64 - 1) - (idx >> 6);        // heavy blocks first
  const int bh = idx & 63;
  const int hh = bh & (NH - 1);
  const int bb = bh >> 4;
  const int q0 = qt * 64;

  const int tid = threadIdx.x;
  const int wave = tid >> 6;
  const int lane = tid & 63;
  const int quad = lane >> 4;
  const int l16 = lane & 15;

  const size_t base = (size_t)bb * SEQ * DIM + hh * HDIM;
  const int qlo = q0 + wave * 16;                    // this wave's first q row

  // Q fragments (A-layout: m=l16, k=quad*8+j), pre-scaled by 1/sqrt(HD)
  bf16x8 qf[2];
  {
    const bf16* qr = q + base + (size_t)(qlo + l16) * DIM;
#pragma unroll
    for (int kc = 0; kc < 2; ++kc) {
      bf16x8 t = *(const bf16x8*)(qr + kc * 32 + quad * 8);
      bf16x8 sq;
#pragma unroll
      for (int e = 0; e < 8; ++e) sq[e] = f2bs(bf2f(t[e]) * 0.125f);
      qf[kc] = sq;
    }
  }

  float l_acc[4] = {0.f, 0.f, 0.f, 0.f};   // per-lane partial sums (rows)
  f32x4 oacc[4];
#pragma unroll
  for (int nb = 0; nb < 4; ++nb) oacc[nb] = (f32x4){0.f, 0.f, 0.f, 0.f};

  short* lPw = lP + wave * 16 * VTS;
  const int nt = qt + 1;

  for (int t = 0; t < nt; ++t) {
    const int kbase = t * 64;
    __syncthreads();   // previous tile's LDS reads complete

    // --- stage K tile [64 keys][64 dims] via g2l16, chunk-swizzled
    {
      const int r8 = lane >> 3;                 // row within 8-row group
      const int cc = (lane & 7) ^ r8;           // swizzled 16B chunk
#pragma unroll
      for (int c = 0; c < 2; ++c) {
        const int row = wave * 16 + c * 8 + r8; // key within tile
        g2l16(k + base + (size_t)(kbase + row) * DIM + cc * 8,
              lK + (wave * 16 + c * 8) * 64);
      }
    }

    // --- stage V^T [dim][key] via regs, kk XOR-swizzled by (dim>>3)&7
    bf16x8 vch[2];
#pragma unroll
    for (int c2 = 0; c2 < 2; ++c2) {
      const int cid = tid + c2 * 256;
      const int kk = cid >> 3;
      const int d0 = (cid & 7) * 8;
      vch[c2] = *(const bf16x8*)(v + base + (size_t)(kbase + kk) * DIM + d0);
    }
#pragma unroll
    for (int c2 = 0; c2 < 2; ++c2) {
      const int cid = tid + c2 * 256;
      const int kk = cid >> 3;
      const int d0 = (cid & 7) * 8;
#pragma unroll
      for (int e = 0; e < 8; ++e) {
        const int d = d0 + e;
        const int kks = kk ^ (((d >> 3) & 7) << 3);
        lVT[d * VTS + kks] = vch[c2][e];
      }
    }
    __builtin_amdgcn_s_waitcnt(0);   // drain g2l16 before barrier
    __syncthreads();

    // --- S = Q K^T : 16 q-rows x 64 keys per wave
    f32x4 s[4];
#pragma unroll
    for (int nb = 0; nb < 4; ++nb) {
      f32x4 acc = (f32x4){0.f, 0.f, 0.f, 0.f};
      const int n = nb * 16 + l16;              // key within tile
#pragma unroll
      for (int kc = 0; kc < 2; ++kc) {
        const int cidx = (kc * 4 + quad) ^ (n & 7);
        bf16x8 kf = *(const bf16x8*)(lK + n * 64 + cidx * 8);
        acc = __builtin_amdgcn_mfma_f32_16x16x32_bf16(qf[kc], kf, acc, 0, 0, 0);
      }
      s[nb] = acc;
    }

    // --- causal mask (only the diagonal tile needs it)
    if (kbase + 63 > qlo) {
#pragma unroll
      for (int nb = 0; nb < 4; ++nb) {
        const int j = kbase + nb * 16 + l16;
#pragma unroll
        for (int r = 0; r < 4; ++r)
          if (j > qlo + quad * 4 + r) s[nb][r] = NEG_BIG;
      }
    }

    // --- fixed-max softmax: p = exp(s); accumulate l per-lane; P -> LDS
#pragma unroll
    for (int nb = 0; nb < 4; ++nb) {
#pragma unroll
      for (int r = 0; r < 4; ++r) {
        const float p = exp_clamped(s[nb][r]);
        l_acc[r] += p;
        lPw[(quad * 4 + r) * VTS + nb * 16 + l16] = f2bs(p);
      }
    }

    // --- P back from LDS in A-layout (same wave; lgkm drain)
    __builtin_amdgcn_s_waitcnt(0);
    bf16x8 pf[2];
#pragma unroll
    for (int kc = 0; kc < 2; ++kc)
      pf[kc] = *(const bf16x8*)(lPw + l16 * VTS + kc * 32 + quad * 8);

    // --- O += P V  (b-frag from V^T rows, undo kk swizzle)
#pragma unroll
    for (int nb = 0; nb < 4; ++nb) {
      const int n = nb * 16 + l16;              // output dim
      const int swz = ((n >> 3) & 7) << 3;
#pragma unroll
      for (int kc = 0; kc < 2; ++kc) {
        const int kchunk = (kc * 32 + quad * 8) ^ swz;
        bf16x8 vf = *(const bf16x8*)(lVT + n * VTS + kchunk);
        oacc[nb] = __builtin_amdgcn_mfma_f32_16x16x32_bf16(pf[kc], vf, oacc[nb], 0, 0, 0);
      }
    }
  }

  // --- reduce l across the 16-lane key groups (once), normalize, store
  float linv[4];
#pragma unroll
  for (int r = 0; r < 4; ++r) {
    float ts = l_acc[r];
#pragma unroll
    for (int off = 8; off >= 1; off >>= 1) ts += __shfl_xor(ts, off);
    linv[r] = 1.f / ts;
  }
#pragma unroll
  for (int nb = 0; nb < 4; ++nb)
#pragma unroll
    for (int r = 0; r < 4; ++r) {
      const int qrow = q0 + wave * 16 + quad * 4 + r;
      o[base + (size_t)qrow * DIM + nb * 16 + l16] =
          __float2bfloat16(oacc[nb][r] * linv[r]);
    }
}

// ---------------------------------------------------------------------------
extern "C" void kernel_launch(void* const* d_in, const int* in_sizes, int n_in,
                              void* d_out, int out_size, void* d_ws, size_t ws_size,
                              hipStream_t stream) {
  const void* x    = d_in[0];
  const void* pe   = d_in[1];
  // d_in[2] = mask (causal; handled analytically; never read)
  const void* ln1g = d_in[3];
  const void* ln1b = d_in[4];
  const void* wq   = d_in[5];
  const void* wk   = d_in[6];
  const void* wv   = d_in[7];
  const void* wo   = d_in[8];
  const void* ln2g = d_in[9];
  const void* ln2b = d_in[10];
  const void* wf   = d_in[11];
  const void* lnfg = d_in[12];
  const void* lnfb = d_in[13];
  const void* wout = d_in[14];

  const size_t MB = 1u << 20;
  char* ws = (char*)d_ws;
  int*  flag = (int*)ws;                          // 4 B (1 MB reserved)
  bf16* wqc  = (bf16*)(ws + 1 * MB);              // 12 MB (6 layers)
  bf16* wkc  = (bf16*)(ws + 13 * MB);
  bf16* wvc  = (bf16*)(ws + 25 * MB);
  bf16* woc  = (bf16*)(ws + 37 * MB);
  bf16* wfc  = (bf16*)(ws + 49 * MB);
  bf16* woutc= (bf16*)(ws + 61 * MB);             // 1 MB
  float* h   = (float*)(ws + 62 * MB);            // 16 MB fp32 residual
  bf16* hn   = (bf16*)(ws + 78 * MB);             // 8 MB
  bf16* qb   = (bf16*)(ws + 86 * MB);
  bf16* kb   = (bf16*)(ws + 94 * MB);
  bf16* vb   = (bf16*)(ws + 102 * MB);            // end: 110 MB
  bf16* ab   = hn;   // attn out aliases hn (ln1 output dead after QKV gemm)

  sniff<<<1, 64, 0, stream>>>((const unsigned int*)wq, flag);

  const int WBLK = (NLAYER * DIM * DIM) / (256 * 8);   // 3072
  convert_w<<<WBLK, 256, 0, stream>>>(wq, wqc, flag);
  convert_w<<<WBLK, 256, 0, stream>>>(wk, wkc, flag);
  convert_w<<<WBLK, 256, 0, stream>>>(wv, wvc, flag);
  convert_w<<<WBLK, 256, 0, stream>>>(wo, woc, flag);
  convert_w<<<WBLK, 256, 0, stream>>>(wf, wfc, flag);
  convert_w<<<(NOUT * DIM) / (256 * 8), 256, 0, stream>>>(wout, woutc, flag);

  add_pe<<<NTOK * DIM / 256, 256, 0, stream>>>(x, pe, h, flag);

  for (int l = 0; l < NLAYER; ++l) {
    const size_t woff = (size_t)l << 20;          // l * 1024*1024 elements
    const int poff = l * DIM;                     // element offset for gamma/beta
    layernorm<<<NTOK, 256, 0, stream>>>(h, ln1g, ln1b, poff, hn, flag);
    gemm_qkv<<<dim3(24, 32), 256, 0, stream>>>(hn, wqc + woff, wkc + woff, wvc + woff,
                                               qb, kb, vb);
    attn_flash<<<dim3(BATCH * NH * (SEQ / 64)), 256, 0, stream>>>(qb, kb, vb, ab);
    gemm_add<<<dim3(8, 32, 2), 256, 0, stream>>>(ab, woc + woff, h);
    layernorm<<<NTOK, 256, 0, stream>>>(h, ln2g, ln2b, poff, hn, flag);
    gemm_add<<<dim3(8, 32, 2), 256, 0, stream>>>(hn, wfc + woff, h);
  }

  layernorm<<<NTOK, 256, 0, stream>>>(h, lnfg, lnfb, 0, hn, flag);
  gemm_out<<<dim3(4, 32), 256, 0, stream>>>(hn, woutc, d_out, flag);
}

// Round 7
// 972.455 us; speedup vs baseline: 1.2241x; 1.2241x over previous
//
#include <hip/hip_runtime.h>
#include <hip/hip_bf16.h>
#include <stdint.h>

// Problem constants: B=4, S=1024, D=1024, H=16, HD=64, L=6, OUT=512
#define BATCH 4
#define SEQ   1024
#define DIM   1024
#define NH    16
#define HDIM  64
#define NLAYER 6
#define NOUT  512
#define NTOK  (BATCH*SEQ)          // 4096 rows
#define LOG2E 1.44269504088896f
#define NEG_BIG (-1e30f)
#define VTS   72                   // padded LDS row stride (elements) for V^T / P

using bf16 = __hip_bfloat16;
typedef __attribute__((ext_vector_type(4))) float f32x4;
typedef __attribute__((ext_vector_type(8))) short bf16x8;

typedef __attribute__((address_space(1))) void as1_void;
typedef __attribute__((address_space(3))) void as3_void;

__device__ __forceinline__ float bf2f(short u) {
  union { unsigned int i; float f; } c;
  c.i = ((unsigned int)(unsigned short)u) << 16;
  return c.f;
}

__device__ __forceinline__ short f2bs(float f) {
  bf16 h = __float2bfloat16(f);
  return *(short*)&h;
}

// inf-free exp: clamp exponent so exp2f never sees huge/inf args (fast-math safe)
__device__ __forceinline__ float exp_clamped(float x) {
  return exp2f(fmaxf(x, -100.f) * LOG2E);
}

// flag-dependent scalar load: fp32 buffer or bf16 buffer
__device__ __forceinline__ float loadf(const void* p, size_t i, bool f32) {
  return f32 ? ((const float*)p)[i] : __bfloat162float(((const bf16*)p)[i]);
}

// async global->LDS, 16B per lane; LDS dest is wave-uniform base + lane*16
__device__ __forceinline__ void g2l16(const void* g, void* l) {
  __builtin_amdgcn_global_load_lds((const as1_void*)g, (as3_void*)l, 16, 0, 0);
}

// ---------------------------------------------------------------------------
// dtype sniffer: flag = 1 -> inputs are fp32 ; flag = 0 -> inputs are bf16
// ---------------------------------------------------------------------------
__global__ void sniff(const unsigned int* __restrict__ w, int* __restrict__ flag) {
  const int lane = threadIdx.x;            // 64 threads
  const unsigned int word = w[lane];
  const int e2 = (word >> 7) & 0xFF;
  const bool bf16ish = (e2 >= 0x60) && (e2 <= 0x8F);
  const unsigned long long m = __ballot(bf16ish);
  if (lane == 0) *flag = (__popcll(m) >= 48) ? 0 : 1;
}

// convert one weight tensor to bf16 workspace (copy if already bf16)
__global__ __launch_bounds__(256) void convert_w(const void* __restrict__ src,
                                                 bf16* __restrict__ dst,
                                                 const int* __restrict__ flag) {
  const size_t i = ((size_t)blockIdx.x * 256 + threadIdx.x) * 8;
  if (*flag) {
    const float* s = (const float*)src + i;
#pragma unroll
    for (int e = 0; e < 8; ++e) dst[i + e] = __float2bfloat16(s[e]);
  } else {
    *(bf16x8*)(dst + i) = *(const bf16x8*)((const bf16*)src + i);
  }
}

// ---------------------------------------------------------------------------
// GEMM 128x128 tile (m97 structure, verified): C = A[M,K] * W[N,K]^T
// EPI 0: store bf16.  EPI 2: flag ? fp32 store : bf16 store.
// ---------------------------------------------------------------------------
template<int EPI>
__device__ __forceinline__ void gemm_body(const bf16* __restrict__ A,
                                          const bf16* __restrict__ W,
                                          void* __restrict__ C,
                                          const int* __restrict__ flag,
                                          int N, int m0, int n0) {
  __shared__ __align__(16) bf16 lA[128 * 32];
  __shared__ __align__(16) bf16 lB[128 * 32];
  const int tid  = threadIdx.x;
  const int wave = tid >> 6;
  const int lane = tid & 63;
  const int quad = lane >> 4;
  const int l16  = lane & 15;
  const int wm = (wave >> 1) * 64;
  const int wn = (wave & 1) * 64;
  const int K = DIM;

  const int r0 = tid >> 2;
  const int c0 = (tid & 3) * 8;
  const int r1 = (tid + 256) >> 2;

  bool f32out = false;
  if (EPI == 2) f32out = (*flag != 0);

  f32x4 acc[4][4];
#pragma unroll
  for (int i = 0; i < 4; ++i)
#pragma unroll
    for (int j = 0; j < 4; ++j) acc[i][j] = (f32x4){0.f, 0.f, 0.f, 0.f};

  for (int k0 = 0; k0 < K; k0 += 32) {
    __syncthreads();
    g2l16(A + (size_t)(m0 + r0) * K + k0 + c0, lA + 512 * wave);
    g2l16(A + (size_t)(m0 + r1) * K + k0 + c0, lA + 2048 + 512 * wave);
    g2l16(W + (size_t)(n0 + r0) * K + k0 + c0, lB + 512 * wave);
    g2l16(W + (size_t)(n0 + r1) * K + k0 + c0, lB + 2048 + 512 * wave);
    __builtin_amdgcn_s_waitcnt(0);
    __syncthreads();

    bf16x8 af[4], bfr[4];
#pragma unroll
    for (int i = 0; i < 4; ++i) {
      af[i]  = *(const bf16x8*)(lA + (wm + i * 16 + l16) * 32 + quad * 8);
      bfr[i] = *(const bf16x8*)(lB + (wn + i * 16 + l16) * 32 + quad * 8);
    }
#pragma unroll
    for (int i = 0; i < 4; ++i)
#pragma unroll
      for (int j = 0; j < 4; ++j)
        acc[i][j] = __builtin_amdgcn_mfma_f32_16x16x32_bf16(af[i], bfr[j], acc[i][j], 0, 0, 0);
  }

  // C/D layout: col = lane&15, row = quad*4 + reg
#pragma unroll
  for (int i = 0; i < 4; ++i) {
    const int rowb = m0 + wm + i * 16 + quad * 4;
#pragma unroll
    for (int j = 0; j < 4; ++j) {
      const int col = n0 + wn + j * 16 + l16;
#pragma unroll
      for (int r = 0; r < 4; ++r) {
        const size_t idx = (size_t)(rowb + r) * N + col;
        const float v = acc[i][j][r];
        if (EPI == 0) ((bf16*)C)[idx] = __float2bfloat16(v);
        else { if (f32out) ((float*)C)[idx] = v; else ((bf16*)C)[idx] = __float2bfloat16(v); }
      }
    }
  }
}

// ---------------------------------------------------------------------------
// GEMM 64x128 tile, full-K, fp32 += epilogue. 512 blocks -> 2 blocks/CU so
// one block's MFMA covers the other's barrier drain (round-6 lesson: split-K
// atomics doubled residual HBM traffic; occupancy must come from tiles).
// Waves in 2x2; each wave 32 rows x 64 cols via acc[2][4].
// ---------------------------------------------------------------------------
__device__ __forceinline__ void gemm64_body(const bf16* __restrict__ A,
                                            const bf16* __restrict__ W,
                                            float* __restrict__ C,
                                            int N, int m0, int n0) {
  __shared__ __align__(16) bf16 lA[64 * 32];
  __shared__ __align__(16) bf16 lB[128 * 32];
  const int tid  = threadIdx.x;
  const int wave = tid >> 6;
  const int lane = tid & 63;
  const int quad = lane >> 4;
  const int l16  = lane & 15;
  const int wm = (wave >> 1) * 32;
  const int wn = (wave & 1) * 64;
  const int K = DIM;

  const int r0 = tid >> 2;             // 0..63
  const int c0 = (tid & 3) * 8;
  const int r1 = (tid + 256) >> 2;     // 64..127 (B second half)

  f32x4 acc[2][4];
#pragma unroll
  for (int i = 0; i < 2; ++i)
#pragma unroll
    for (int j = 0; j < 4; ++j) acc[i][j] = (f32x4){0.f, 0.f, 0.f, 0.f};

  for (int k0 = 0; k0 < K; k0 += 32) {
    __syncthreads();
    g2l16(A + (size_t)(m0 + r0) * K + k0 + c0, lA + 512 * wave);
    g2l16(W + (size_t)(n0 + r0) * K + k0 + c0, lB + 512 * wave);
    g2l16(W + (size_t)(n0 + r1) * K + k0 + c0, lB + 2048 + 512 * wave);
    __builtin_amdgcn_s_waitcnt(0);
    __syncthreads();

    bf16x8 af[2], bfr[4];
#pragma unroll
    for (int i = 0; i < 2; ++i)
      af[i]  = *(const bf16x8*)(lA + (wm + i * 16 + l16) * 32 + quad * 8);
#pragma unroll
    for (int j = 0; j < 4; ++j)
      bfr[j] = *(const bf16x8*)(lB + (wn + j * 16 + l16) * 32 + quad * 8);
#pragma unroll
    for (int i = 0; i < 2; ++i)
#pragma unroll
      for (int j = 0; j < 4; ++j)
        acc[i][j] = __builtin_amdgcn_mfma_f32_16x16x32_bf16(af[i], bfr[j], acc[i][j], 0, 0, 0);
  }

#pragma unroll
  for (int i = 0; i < 2; ++i) {
    const int rowb = m0 + wm + i * 16 + quad * 4;
#pragma unroll
    for (int j = 0; j < 4; ++j) {
      const int col = n0 + wn + j * 16 + l16;
#pragma unroll
      for (int r = 0; r < 4; ++r)
        C[(size_t)(rowb + r) * N + col] += acc[i][j][r];
    }
  }
}

__global__ __launch_bounds__(256) void gemm_out(const bf16* __restrict__ A,
                                                const bf16* __restrict__ W,
                                                void* __restrict__ C,
                                                const int* __restrict__ flag) {
  gemm_body<2>(A, W, C, flag, NOUT, blockIdx.y * 128, blockIdx.x * 128);
}

__global__ __launch_bounds__(256) void gemm_add(const bf16* __restrict__ A,
                                                const bf16* __restrict__ W,
                                                float* __restrict__ C) {
  gemm64_body(A, W, C, DIM, blockIdx.y * 64, blockIdx.x * 128);
}

__global__ __launch_bounds__(256) void gemm_qkv(const bf16* __restrict__ A,
                                                const bf16* __restrict__ wq,
                                                const bf16* __restrict__ wk,
                                                const bf16* __restrict__ wv,
                                                bf16* __restrict__ q,
                                                bf16* __restrict__ k,
                                                bf16* __restrict__ v) {
  const int gx = blockIdx.x;
  const int sel = gx >> 3;
  const int n0 = (gx & 7) * 128;
  const bf16* W = (sel == 0) ? wq : (sel == 1 ? wk : wv);
  bf16* C = (sel == 0) ? q : (sel == 1 ? k : v);
  gemm_body<0>(A, W, C, nullptr, DIM, blockIdx.y * 128, n0);
}

// ---------------------------------------------------------------------------
// h = x + pe  (flag-dependent input dtype), fp32 residual stream
// ---------------------------------------------------------------------------
__global__ __launch_bounds__(256) void add_pe(const void* __restrict__ x,
                                              const void* __restrict__ pe,
                                              float* __restrict__ h,
                                              const int* __restrict__ flag) {
  const bool f32 = (*flag != 0);
  const size_t i = (size_t)blockIdx.x * 256 + threadIdx.x;
  h[i] = loadf(x, i, f32) + loadf(pe, i & (SEQ * DIM - 1), f32);
}

// ---------------------------------------------------------------------------
// LayerNorm over D=1024: one 256-thread block per row, fp32 in, bf16 out.
// ---------------------------------------------------------------------------
__global__ __launch_bounds__(256) void layernorm(const float* __restrict__ x,
                                                 const void* __restrict__ g,
                                                 const void* __restrict__ b,
                                                 int loff,
                                                 bf16* __restrict__ y,
                                                 const int* __restrict__ flag) {
  const bool f32 = (*flag != 0);
  const int row = blockIdx.x;
  const int tid = threadIdx.x;
  const int wave = tid >> 6;
  const float* xr = x + (size_t)row * DIM;
  __shared__ float red[8];

  float v[4];
  float s = 0.f;
#pragma unroll
  for (int i = 0; i < 4; ++i) { v[i] = xr[tid + 256 * i]; s += v[i]; }
#pragma unroll
  for (int off = 32; off >= 1; off >>= 1) s += __shfl_xor(s, off);
  if ((tid & 63) == 0) red[wave] = s;
  __syncthreads();
  const float mu = (red[0] + red[1] + red[2] + red[3]) * (1.f / DIM);

  float vs = 0.f;
#pragma unroll
  for (int i = 0; i < 4; ++i) { const float d = v[i] - mu; vs += d * d; }
#pragma unroll
  for (int off = 32; off >= 1; off >>= 1) vs += __shfl_xor(vs, off);
  if ((tid & 63) == 0) red[4 + wave] = vs;
  __syncthreads();
  const float var = (red[4] + red[5] + red[6] + red[7]) * (1.f / DIM);
  const float rs = rsqrtf(var + 1e-5f);

#pragma unroll
  for (int i = 0; i < 4; ++i) {
    const int d = tid + 256 * i;
    const float gv = loadf(g, (size_t)loff + d, f32);
    const float bv = loadf(b, (size_t)loff + d, f32);
    y[(size_t)row * DIM + d] = __float2bfloat16((v[i] - mu) * rs * gv + bv);
  }
}

// ---------------------------------------------------------------------------
// MFMA flash attention, FIXED-MAX softmax (m=0): scores bounded (|s|<=26),
// so no max reduction, no alpha rescale; l reduced once at the end.
// Block = (b, h, 64 q-rows); 4 waves, 16 q-rows/wave.
// ---------------------------------------------------------------------------
__global__ __launch_bounds__(256, 2) void attn_flash(const bf16* __restrict__ q,
                                                     const bf16* __restrict__ k,
                                                     const bf16* __restrict__ v,
                                                     bf16* __restrict__ o) {
  __shared__ __align__(16) short lK[64 * 64];        // [key][dim], chunk-swizzled
  __shared__ __align__(16) short lVT[64 * VTS];      // [dim][key], kk-swizzled
  __shared__ __align__(16) short lP[4 * 16 * VTS];   // per-wave P, padded

  const int idx = blockIdx.x;
  const int qt = (SEQ / 64 - 1) - (idx >> 6);        // heavy blocks first
  const int bh = idx & 63;
  const int hh = bh & (NH - 1);
  const int bb = bh >> 4;
  const int q0 = qt * 64;

  const int tid = threadIdx.x;
  const int wave = tid >> 6;
  const int lane = tid & 63;
  const int quad = lane >> 4;
  const int l16 = lane & 15;

  const size_t base = (size_t)bb * SEQ * DIM + hh * HDIM;
  const int qlo = q0 + wave * 16;                    // this wave's first q row

  // Q fragments (A-layout: m=l16, k=quad*8+j), pre-scaled by 1/sqrt(HD)
  bf16x8 qf[2];
  {
    const bf16* qr = q + base + (size_t)(qlo + l16) * DIM;
#pragma unroll
    for (int kc = 0; kc < 2; ++kc) {
      bf16x8 t = *(const bf16x8*)(qr + kc * 32 + quad * 8);
      bf16x8 sq;
#pragma unroll
      for (int e = 0; e < 8; ++e) sq[e] = f2bs(bf2f(t[e]) * 0.125f);
      qf[kc] = sq;
    }
  }

  float l_acc[4] = {0.f, 0.f, 0.f, 0.f};   // per-lane partial sums (rows)
  f32x4 oacc[4];
#pragma unroll
  for (int nb = 0; nb < 4; ++nb) oacc[nb] = (f32x4){0.f, 0.f, 0.f, 0.f};

  short* lPw = lP + wave * 16 * VTS;
  const int nt = qt + 1;

  for (int t = 0; t < nt; ++t) {
    const int kbase = t * 64;
    __syncthreads();   // previous tile's LDS reads complete

    // --- stage K tile [64 keys][64 dims] via g2l16, chunk-swizzled
    {
      const int r8 = lane >> 3;                 // row within 8-row group
      const int cc = (lane & 7) ^ r8;           // swizzled 16B chunk
#pragma unroll
      for (int c = 0; c < 2; ++c) {
        const int row = wave * 16 + c * 8 + r8; // key within tile
        g2l16(k + base + (size_t)(kbase + row) * DIM + cc * 8,
              lK + (wave * 16 + c * 8) * 64);
      }
    }

    // --- stage V^T [dim][key] via regs, kk XOR-swizzled by (dim>>3)&7
    bf16x8 vch[2];
#pragma unroll
    for (int c2 = 0; c2 < 2; ++c2) {
      const int cid = tid + c2 * 256;
      const int kk = cid >> 3;
      const int d0 = (cid & 7) * 8;
      vch[c2] = *(const bf16x8*)(v + base + (size_t)(kbase + kk) * DIM + d0);
    }
#pragma unroll
    for (int c2 = 0; c2 < 2; ++c2) {
      const int cid = tid + c2 * 256;
      const int kk = cid >> 3;
      const int d0 = (cid & 7) * 8;
#pragma unroll
      for (int e = 0; e < 8; ++e) {
        const int d = d0 + e;
        const int kks = kk ^ (((d >> 3) & 7) << 3);
        lVT[d * VTS + kks] = vch[c2][e];
      }
    }
    __builtin_amdgcn_s_waitcnt(0);   // drain g2l16 before barrier
    __syncthreads();

    // --- S = Q K^T : 16 q-rows x 64 keys per wave
    f32x4 s[4];
#pragma unroll
    for (int nb = 0; nb < 4; ++nb) {
      f32x4 acc = (f32x4){0.f, 0.f, 0.f, 0.f};
      const int n = nb * 16 + l16;              // key within tile
#pragma unroll
      for (int kc = 0; kc < 2; ++kc) {
        const int cidx = (kc * 4 + quad) ^ (n & 7);
        bf16x8 kf = *(const bf16x8*)(lK + n * 64 + cidx * 8);
        acc = __builtin_amdgcn_mfma_f32_16x16x32_bf16(qf[kc], kf, acc, 0, 0, 0);
      }
      s[nb] = acc;
    }

    // --- causal mask (only the diagonal tile needs it)
    if (kbase + 63 > qlo) {
#pragma unroll
      for (int nb = 0; nb < 4; ++nb) {
        const int j = kbase + nb * 16 + l16;
#pragma unroll
        for (int r = 0; r < 4; ++r)
          if (j > qlo + quad * 4 + r) s[nb][r] = NEG_BIG;
      }
    }

    // --- fixed-max softmax: p = exp(s); accumulate l per-lane; P -> LDS
#pragma unroll
    for (int nb = 0; nb < 4; ++nb) {
#pragma unroll
      for (int r = 0; r < 4; ++r) {
        const float p = exp_clamped(s[nb][r]);
        l_acc[r] += p;
        lPw[(quad * 4 + r) * VTS + nb * 16 + l16] = f2bs(p);
      }
    }

    // --- P back from LDS in A-layout (same wave; lgkm drain)
    __builtin_amdgcn_s_waitcnt(0);
    bf16x8 pf[2];
#pragma unroll
    for (int kc = 0; kc < 2; ++kc)
      pf[kc] = *(const bf16x8*)(lPw + l16 * VTS + kc * 32 + quad * 8);

    // --- O += P V  (b-frag from V^T rows, undo kk swizzle)
#pragma unroll
    for (int nb = 0; nb < 4; ++nb) {
      const int n = nb * 16 + l16;              // output dim
      const int swz = ((n >> 3) & 7) << 3;
#pragma unroll
      for (int kc = 0; kc < 2; ++kc) {
        const int kchunk = (kc * 32 + quad * 8) ^ swz;
        bf16x8 vf = *(const bf16x8*)(lVT + n * VTS + kchunk);
        oacc[nb] = __builtin_amdgcn_mfma_f32_16x16x32_bf16(pf[kc], vf, oacc[nb], 0, 0, 0);
      }
    }
  }

  // --- reduce l across the 16-lane key groups (once), normalize, store
  float linv[4];
#pragma unroll
  for (int r = 0; r < 4; ++r) {
    float ts = l_acc[r];
#pragma unroll
    for (int off = 8; off >= 1; off >>= 1) ts += __shfl_xor(ts, off);
    linv[r] = 1.f / ts;
  }
#pragma unroll
  for (int nb = 0; nb < 4; ++nb)
#pragma unroll
    for (int r = 0; r < 4; ++r) {
      const int qrow = q0 + wave * 16 + quad * 4 + r;
      o[base + (size_t)qrow * DIM + nb * 16 + l16] =
          __float2bfloat16(oacc[nb][r] * linv[r]);
    }
}

// ---------------------------------------------------------------------------
extern "C" void kernel_launch(void* const* d_in, const int* in_sizes, int n_in,
                              void* d_out, int out_size, void* d_ws, size_t ws_size,
                              hipStream_t stream) {
  const void* x    = d_in[0];
  const void* pe   = d_in[1];
  // d_in[2] = mask (causal; handled analytically; never read)
  const void* ln1g = d_in[3];
  const void* ln1b = d_in[4];
  const void* wq   = d_in[5];
  const void* wk   = d_in[6];
  const void* wv   = d_in[7];
  const void* wo   = d_in[8];
  const void* ln2g = d_in[9];
  const void* ln2b = d_in[10];
  const void* wf   = d_in[11];
  const void* lnfg = d_in[12];
  const void* lnfb = d_in[13];
  const void* wout = d_in[14];

  const size_t MB = 1u << 20;
  char* ws = (char*)d_ws;
  int*  flag = (int*)ws;                          // 4 B (1 MB reserved)
  bf16* wqc  = (bf16*)(ws + 1 * MB);              // 12 MB (6 layers)
  bf16* wkc  = (bf16*)(ws + 13 * MB);
  bf16* wvc  = (bf16*)(ws + 25 * MB);
  bf16* woc  = (bf16*)(ws + 37 * MB);
  bf16* wfc  = (bf16*)(ws + 49 * MB);
  bf16* woutc= (bf16*)(ws + 61 * MB);             // 1 MB
  float* h   = (float*)(ws + 62 * MB);            // 16 MB fp32 residual
  bf16* hn   = (bf16*)(ws + 78 * MB);             // 8 MB
  bf16* qb   = (bf16*)(ws + 86 * MB);
  bf16* kb   = (bf16*)(ws + 94 * MB);
  bf16* vb   = (bf16*)(ws + 102 * MB);            // end: 110 MB
  bf16* ab   = hn;   // attn out aliases hn (ln1 output dead after QKV gemm)

  sniff<<<1, 64, 0, stream>>>((const unsigned int*)wq, flag);

  const int WBLK = (NLAYER * DIM * DIM) / (256 * 8);   // 3072
  convert_w<<<WBLK, 256, 0, stream>>>(wq, wqc, flag);
  convert_w<<<WBLK, 256, 0, stream>>>(wk, wkc, flag);
  convert_w<<<WBLK, 256, 0, stream>>>(wv, wvc, flag);
  convert_w<<<WBLK, 256, 0, stream>>>(wo, woc, flag);
  convert_w<<<WBLK, 256, 0, stream>>>(wf, wfc, flag);
  convert_w<<<(NOUT * DIM) / (256 * 8), 256, 0, stream>>>(wout, woutc, flag);

  add_pe<<<NTOK * DIM / 256, 256, 0, stream>>>(x, pe, h, flag);

  for (int l = 0; l < NLAYER; ++l) {
    const size_t woff = (size_t)l << 20;          // l * 1024*1024 elements
    const int poff = l * DIM;                     // element offset for gamma/beta
    layernorm<<<NTOK, 256, 0, stream>>>(h, ln1g, ln1b, poff, hn, flag);
    gemm_qkv<<<dim3(24, 32), 256, 0, stream>>>(hn, wqc + woff, wkc + woff, wvc + woff,
                                               qb, kb, vb);
    attn_flash<<<dim3(BATCH * NH * (SEQ / 64)), 256, 0, stream>>>(qb, kb, vb, ab);
    gemm_add<<<dim3(8, 64), 256, 0, stream>>>(ab, woc + woff, h);
    layernorm<<<NTOK, 256, 0, stream>>>(h, ln2g, ln2b, poff, hn, flag);
    gemm_add<<<dim3(8, 64), 256, 0, stream>>>(hn, wfc + woff, h);
  }

  layernorm<<<NTOK, 256, 0, stream>>>(h, lnfg, lnfb, 0, hn, flag);
  gemm_out<<<dim3(4, 32), 256, 0, stream>>>(hn, woutc, d_out, flag);
}